// Round 20
// baseline (190.795 us; speedup 1.0000x reference)
//
#include <hip/hip_runtime.h>

typedef __attribute__((ext_vector_type(8))) short bf16x8;
typedef __attribute__((ext_vector_type(4))) float f32x4;

__device__ __forceinline__ unsigned short f2bf(float f) {
  unsigned int u = __builtin_bit_cast(unsigned int, f);
  u += 0x7fffu + ((u >> 16) & 1u);   // RNE
  return (unsigned short)(u >> 16);
}

#define GLD16(gp, lp) __builtin_amdgcn_global_load_lds( \
    (const __attribute__((address_space(1))) unsigned int*)(gp), \
    (__attribute__((address_space(3))) unsigned int*)(lp), 16, 0, 0)

// ---------------------------------------------------------------------------
// Grid-stride prep (G11): 2048 blocks x 256. Each block: ballot mask-pack
// slice (8-deep load ILP) + 8 grid-stride float4 converts + grid-stride
// weight copies + sums zeroing (first 64 blocks).
__global__ __launch_bounds__(256) void prep_all(
    const unsigned char* __restrict__ m, unsigned long long* __restrict__ pm,
    const float* __restrict__ query, const float* __restrict__ node,
    const float* __restrict__ wq, const float* __restrict__ wk,
    const float* __restrict__ wv,
    unsigned short* __restrict__ Xq, unsigned short* __restrict__ Xn,
    unsigned short* __restrict__ wqb, unsigned short* __restrict__ wkb,
    unsigned short* __restrict__ wvt, float* __restrict__ sums)
{
  const int b = blockIdx.x;          // 0..2047
  const int t = threadIdx.x;

  // ---- (a) mask pack, ballot form with 8-deep ILP ----
  // Mode probe: one u32/thread (int32 view). int32 0/1 -> byte1 always 0;
  // bool -> byte1 nonzero with p=0.3/word (P(miss over 256) = 0.7^256 ~ 0).
  __shared__ int mode1;
  if (t == 0) mode1 = 0;
  __syncthreads();
  const unsigned int* m32 = (const unsigned int*)m;
  unsigned int pw = m32[(size_t)b * 4096 + t];
  if (pw & 0x0000ff00u) mode1 = 1;   // benign race
  __syncthreads();

  {
    const int w = t >> 6;
    const int l = t & 63;
    const long gbase = (long)b * 256 + w * 64;
    unsigned long long myw = 0;
    if (mode1) {
      for (int it0 = 0; it0 < 64; it0 += 8) {
        unsigned char v[8];
#pragma unroll
        for (int j = 0; j < 8; ++j)
          v[j] = m[(gbase + it0 + j) * 64 + l];       // 8 loads in flight
#pragma unroll
        for (int j = 0; j < 8; ++j) {
          const unsigned long long bal = __ballot(v[j] != 0);
          if (l == it0 + j) myw = bal;
        }
      }
    } else {
      for (int it0 = 0; it0 < 64; it0 += 8) {
        unsigned int v[8];
#pragma unroll
        for (int j = 0; j < 8; ++j)
          v[j] = m32[(gbase + it0 + j) * 64 + l];     // 8 x 256B/wave in flight
#pragma unroll
        for (int j = 0; j < 8; ++j) {
          const unsigned long long bal = __ballot(v[j] != 0);
          if (l == it0 + j) myw = bal;
        }
      }
    }
    pm[gbase + l] = myw;             // coalesced 512 B/wave
  }

  // ---- (b) activation converts, grid-stride (8 float4s/thread) ----
  {
    const int stride = 2048 * 256;
#pragma unroll
    for (int r = 0; r < 8; ++r) {
      int i = b * 256 + t + r * stride;      // 0..4194303
      const float* src;
      unsigned short* dst;
      int j;
      if (i < 2097152) { src = query; dst = Xq; j = i; }
      else             { src = node;  dst = Xn; j = i - 2097152; }
      float4 v = ((const float4*)src)[j];
      ushort4 o;
      o.x = f2bf(v.x); o.y = f2bf(v.y); o.z = f2bf(v.z); o.w = f2bf(v.w);
      ((ushort4*)dst)[j] = o;
    }
  }

  // ---- (c) weight copies, grid-stride ----
  for (int idx = b * 256 + t; idx < 786432; idx += 2048 * 256) {
    int w = idx >> 18;
    int rem = idx & 262143;
    if (w == 0)      wqb[rem] = f2bf(wq[rem]);
    else if (w == 1) wkb[rem] = f2bf(wk[rem]);
    else {
      int n = rem >> 9, k = rem & 511;
      wvt[n * 512 + k] = f2bf(wv[k * 512 + n]);
    }
  }

  // ---- (d) sums zeroing (first 64 blocks) ----
  {
    int idx = b * 256 + t;
    if (idx < 16384) sums[idx] = 0.0f;
  }
}

// ---------------------------------------------------------------------------
// Unified 128x128 core, 3 blocks/CU (r12/r14/r15-verified): BK=32, 4 waves,
// 3 bufs x 16KB = 48KB LDS. Stage t+2 during t; vmcnt ledger 8/4/0 (L=4).
// Swizzle: 16B-chunk ^= ((row>>1)&3) -> 2-way max (conflict-count 0, r14).
// mode 0: bf16 C. mode 1: scores epilogue (bitmask exp + rowsum atomics).
// mode 2: f32 C scaled by 1/sums[row].
__device__ __forceinline__ void core128(
    const unsigned short* __restrict__ Ab, const unsigned short* __restrict__ Bb,
    void* __restrict__ Cb, long ldA, long ldB, long ldO, int nk,
    long bm, long bn, char* smem, int mode,
    const unsigned long long* __restrict__ pmask, float* __restrict__ sumz,
    const float* __restrict__ sums_ro)
{
  const int tid = threadIdx.x;          // 0..255
  const int lane = tid & 63;
  const int wid = tid >> 6;
  const int wr = wid >> 1, wc = wid & 1;
  const int fr = lane & 15, fq = lane >> 4;

  const int srow = tid >> 2;            // 0..63
  const int sch = (tid & 3) ^ ((srow >> 1) & 3);   // pre-swizzled source chunk

  char* bufs[3] = { smem, smem + 16384, smem + 32768 };

#define STAGE_C(buf, kt) do { \
    const long k0_ = (long)(kt) << 5; \
    GLD16(Ab + (bm + srow) * ldA + k0_ + sch * 8,        (buf) + tid * 16); \
    GLD16(Ab + (bm + 64 + srow) * ldA + k0_ + sch * 8,   (buf) + 4096 + tid * 16); \
    GLD16(Bb + (bn + srow) * ldB + k0_ + sch * 8,        (buf) + 8192 + tid * 16); \
    GLD16(Bb + (bn + 64 + srow) * ldB + k0_ + sch * 8,   (buf) + 12288 + tid * 16); \
  } while (0)

  int aoff[4], boff[4];
#pragma unroll
  for (int i = 0; i < 4; ++i) {
    const int ra = wr * 64 + i * 16 + fr;
    aoff[i] = ra * 64 + (fq ^ ((ra >> 1) & 3)) * 16;
    const int rb = wc * 64 + i * 16 + fr;
    boff[i] = 8192 + rb * 64 + (fq ^ ((rb >> 1) & 3)) * 16;
  }

  f32x4 acc[4][4] = {};

  STAGE_C(bufs[0], 0);
  STAGE_C(bufs[1], 1);
  char* c0 = bufs[0]; char* c1 = bufs[1]; char* c2 = bufs[2];

  for (int t = 0; t < nk; ++t) {
    __builtin_amdgcn_sched_barrier(0);
    __builtin_amdgcn_s_barrier();       // B1: all reads of c2's old tile done
    if (t + 2 < nk) {
      STAGE_C(c2, t + 2);
      asm volatile("s_waitcnt vmcnt(8)" ::: "memory");   // tile t landed
    } else if (t + 2 == nk) {
      asm volatile("s_waitcnt vmcnt(4)" ::: "memory");
    } else {
      asm volatile("s_waitcnt vmcnt(0)" ::: "memory");
    }
    __builtin_amdgcn_s_barrier();       // B2: tile t visible to all waves
    __builtin_amdgcn_sched_barrier(0);

    bf16x8 a[4];
#pragma unroll
    for (int mi = 0; mi < 4; ++mi)
      a[mi] = *(const bf16x8*)(c0 + aoff[mi]);
    __builtin_amdgcn_s_setprio(1);
#pragma unroll
    for (int nj = 0; nj < 4; ++nj) {
      const bf16x8 b = *(const bf16x8*)(c0 + boff[nj]);
#pragma unroll
      for (int mi = 0; mi < 4; ++mi)
        acc[mi][nj] = __builtin_amdgcn_mfma_f32_16x16x32_bf16(a[mi], b, acc[mi][nj], 0, 0, 0);
    }
    __builtin_amdgcn_s_setprio(0);

    char* tmp = c0; c0 = c1; c1 = c2; c2 = tmp;
  }
#undef STAGE_C

  // Epilogue. C/D layout: col=lane&15, row=(lane>>4)*4+r  [m89-verified]
  const float SCALE = 0.04419417382415922f;  // 1/sqrt(512)
  if (mode == 0) {
    unsigned short* C = (unsigned short*)Cb;
#pragma unroll
    for (int mi = 0; mi < 4; ++mi)
#pragma unroll
      for (int nj = 0; nj < 4; ++nj) {
        const long row = bm + wr * 64 + mi * 16 + fq * 4;
        const long col = bn + wc * 64 + nj * 16 + fr;
#pragma unroll
        for (int r = 0; r < 4; ++r)
          C[(row + r) * ldO + col] = f2bf(acc[mi][nj][r]);
      }
  } else if (mode == 1) {
    unsigned short* C = (unsigned short*)Cb;
    const long wword = (bn >> 6) + wc;
#pragma unroll
    for (int mi = 0; mi < 4; ++mi) {
      const long rowb = bm + wr * 64 + mi * 16 + fq * 4;
#pragma unroll
      for (int r = 0; r < 4; ++r) {
        const long row = rowb + r;
        const unsigned long long w = pmask[row * 32 + wword];
        unsigned short* Crow = C + row * ldO + bn + wc * 64 + fr;
        float s = 0.f;
#pragma unroll
        for (int nj = 0; nj < 4; ++nj) {
          const int sh = nj * 16 + fr;
          float e = ((w >> sh) & 1ull) ? 0.0f : __expf(acc[mi][nj][r] * SCALE);
          s += e;
          Crow[nj * 16] = f2bf(e);
        }
        s += __shfl_xor(s, 1); s += __shfl_xor(s, 2);
        s += __shfl_xor(s, 4); s += __shfl_xor(s, 8);
        if (fr == 0) atomicAdd(&sumz[row], s);
      }
    }
  } else {
    float* C = (float*)Cb;
#pragma unroll
    for (int mi = 0; mi < 4; ++mi) {
      const long rowb = bm + wr * 64 + mi * 16 + fq * 4;
#pragma unroll
      for (int r = 0; r < 4; ++r) {
        const long row = rowb + r;
        const float iv = 1.0f / sums_ro[row];
        const long colb = bn + wc * 64 + fr;
#pragma unroll
        for (int nj = 0; nj < 4; ++nj)
          C[row * ldO + colb + nj * 16] = acc[mi][nj][r] * iv;
      }
    }
  }
}

// MT = Wk_bf * Wq_bf^T  (= M^T where M = Wq*Wk^T). grid(4,4,1).
__global__ __launch_bounds__(256, 3) void gemm_mt(
    const unsigned short* __restrict__ wkb, const unsigned short* __restrict__ wqb,
    unsigned short* __restrict__ MT)
{
  extern __shared__ char smem[];
  core128(wkb, wqb, MT, 512, 512, 512, 16,
          (long)blockIdx.x * 128, (long)blockIdx.y * 128, smem, 0,
          nullptr, nullptr, nullptr);
}

// Projections, grid(128,4,2): z=0: T = Xq*MT^T; z=1: Vt = Wvt*Xn^T [512x16384]
__global__ __launch_bounds__(256, 3) void gemm_proj(
    const unsigned short* __restrict__ Xq, const unsigned short* __restrict__ Xn,
    const unsigned short* __restrict__ MT, const unsigned short* __restrict__ Wvt,
    unsigned short* __restrict__ T, unsigned short* __restrict__ Vt)
{
  extern __shared__ char smem[];
  if (blockIdx.z == 0) {
    core128(Xq, MT, T, 512, 512, 512, 16,
            (long)blockIdx.x * 128, (long)blockIdx.y * 128, smem, 0,
            nullptr, nullptr, nullptr);
  } else {
    core128(Wvt, Xn, Vt, 512, 512, 16384, 16,
            (long)blockIdx.y * 128, (long)blockIdx.x * 128, smem, 0,
            nullptr, nullptr, nullptr);
  }
}

// Scores: E = masked?0:exp((T Xn^T)*scale) + rowsum atomics.
// grid(8,16,16): x=batch=XCD (T/Xn slices L2-resident), y=q panel, z=kv panel.
__global__ __launch_bounds__(256, 3) void gemm_scores(
    const unsigned short* __restrict__ T, const unsigned short* __restrict__ Xn,
    unsigned short* __restrict__ Eg, const unsigned long long* __restrict__ pm,
    float* __restrict__ sums)
{
  extern __shared__ char smem[];
  const long z = blockIdx.x;
  core128(T + z * 1048576, Xn + z * 1048576, Eg + z * 4194304,
          512, 512, 2048, 16,
          (long)blockIdx.y * 128, (long)blockIdx.z * 128, smem, 1,
          pm + z * 65536, sums + z * 2048, nullptr);
}

// PV: O = (E @ V) / rowsum, f32. grid(8,4,16): x=batch=XCD, y=d panel
// (FASTEST -> E panel L2-shared by 4 consecutive blocks, Vt slice resident),
// z=q panel.
__global__ __launch_bounds__(256, 3) void gemm_pv(
    const unsigned short* __restrict__ E, const unsigned short* __restrict__ Vt,
    const float* __restrict__ sums, float* __restrict__ O)
{
  extern __shared__ char smem[];
  const long z = blockIdx.x;                    // batch = XCD
  core128(E + z * 4194304, Vt + z * 2048, O + z * 1048576,
          2048, 16384, 512, 64,
          (long)blockIdx.z * 128, (long)blockIdx.y * 128, smem, 2,
          nullptr, nullptr, sums + z * 2048);
}

// ---------------------------------------------------------------------------
extern "C" void kernel_launch(void* const* d_in, const int* in_sizes, int n_in,
                              void* d_out, int out_size, void* d_ws, size_t ws_size,
                              hipStream_t stream) {
  const float* node  = (const float*)d_in[0];
  const float* query = (const float*)d_in[1];
  const unsigned char* mask = (const unsigned char*)d_in[2];
  const float* wq = (const float*)d_in[3];
  const float* wk = (const float*)d_in[4];
  const float* wv = (const float*)d_in[5];
  float* out = (float*)d_out;

  char* ws = (char*)d_ws;
  // ws: T @0 (16M) | Xn @16M (16M) | Vt @32M (16M) | E @48M..112M (64M)
  //     overlapped, dead before scores: Xq @48M; wqb/wkb/Wvt/MT @64M+
  //     sums @112M (64K) | pm @~113M (4M)
  unsigned short* T   = (unsigned short*)(ws);
  unsigned short* Xn  = (unsigned short*)(ws + 16777216);
  unsigned short* Vt  = (unsigned short*)(ws + 33554432);
  unsigned short* E   = (unsigned short*)(ws + 50331648);
  unsigned short* Xq  = (unsigned short*)(ws + 50331648);           // dead after T-proj
  unsigned short* wqb = (unsigned short*)(ws + 67108864);           // dead after MT
  unsigned short* wkb = (unsigned short*)(ws + 67633152);           // dead after MT
  unsigned short* Wvt = (unsigned short*)(ws + 68157440);           // dead after proj
  unsigned short* MT  = (unsigned short*)(ws + 68681728);           // dead after proj
  float* sums = (float*)(ws + 117440512);
  unsigned long long* pm = (unsigned long long*)(ws + 118489088);

  // One grid-stride prep launch (G11): 2048 blocks
  prep_all<<<2048, 256, 0, stream>>>(mask, pm, query, node, wq, wk, wv,
                                     Xq, Xn, wqb, wkb, Wvt, sums);

  // MT = Wk*Wq^T (512x512 tiny GEMM)
  gemm_mt<<<dim3(4, 4, 1), 256, 49152, stream>>>(wkb, wqb, MT);

  // Projections: T = Xq*MT^T and Vt = Wvt*Xn^T (K-projection eliminated by
  // associativity: S = Xq*(Wq Wk^T)*Xn^T)
  dim3 gp(128, 4, 2);
  gemm_proj<<<gp, 256, 49152, stream>>>(Xq, Xn, MT, Wvt, T, Vt);

  // Scores (+exp +mask +row sums): 2048 blocks
  dim3 gs(8, 16, 16);
  gemm_scores<<<gs, 256, 49152, stream>>>(T, Xn, E, pm, sums);

  // PV + normalize: 512 blocks, d-panel fastest per XCD
  dim3 gv(8, 4, 16);
  gemm_pv<<<gv, 256, 49152, stream>>>(E, Vt, sums, out);
}